// Round 6
// baseline (300.166 us; speedup 1.0000x reference)
//
#include <hip/hip_runtime.h>

typedef __attribute__((ext_vector_type(8))) short short8;
typedef __attribute__((ext_vector_type(4))) short short4_t;
typedef __attribute__((ext_vector_type(4))) float f32x4;
typedef __attribute__((ext_vector_type(4))) unsigned short u16x4;

__device__ __forceinline__ unsigned short f2b(float f) {
  unsigned int u = __float_as_uint(f);
  u += 0x7fffu + ((u >> 16) & 1u);   // RNE
  return (unsigned short)(u >> 16);
}
__device__ __forceinline__ float b2f(unsigned short s) {
  return __uint_as_float(((unsigned int)s) << 16);
}
__device__ __forceinline__ void glds16(const void* g, void* l) {
  __builtin_amdgcn_global_load_lds(
      (const __attribute__((address_space(1))) unsigned int*)g,
      (__attribute__((address_space(3))) unsigned int*)l, 16, 0, 0);
}

// ------------------------------------------------- fused cast: all 5 inputs -> bf16
__global__ __launch_bounds__(256) void cast_all(const float* __restrict__ x,
                                                const float* __restrict__ wq,
                                                const float* __restrict__ wk,
                                                const float* __restrict__ wv,
                                                const float* __restrict__ wo,
                                                unsigned short* __restrict__ dst) {
  const int i = blockIdx.x * 256 + threadIdx.x;   // < 4,718,592 (grid exact)
  const float* s;
  int off;
  if (i < 2097152)      { s = x;  off = i; }
  else if (i < 3145728) { s = wq; off = i - 2097152; }
  else if (i < 3407872) { s = wk; off = i - 3145728; }
  else if (i < 3670016) { s = wv; off = i - 3407872; }
  else                  { s = wo; off = i - 3670016; }
  f32x4 v = ((const f32x4*)s)[off];
  u16x4 o;
  o[0] = f2b(v[0]); o[1] = f2b(v[1]); o[2] = f2b(v[2]); o[3] = f2b(v[3]);
  ((u16x4*)dst)[i] = o;
}

// ------------------------------------------------- GEMM Q/K tiles + fused RoPE
// C = x @ Wqkv^T restricted to n-tiles 0..19 (16 q heads + 4 k heads), K=2048.
// Wave column groups ngrp = (w&1)*2 + (ni&1) + (ni>>1)*4: each thread holds rope
// partners (d, d+64) as acc[mi][ni] / acc[mi][ni+2] (ni<2) -> thread-local RoPE.
// Single straight-line epilogue (split from the V kernel so the allocator can
// keep accs in AGPRs during the K-loop; round-4/5's branchy epilogue -> VGPR 116).
__global__ __launch_bounds__(256) void gemm_qk(const unsigned short* __restrict__ A,
                                               const unsigned short* __restrict__ B,
                                               unsigned short* __restrict__ qb,
                                               unsigned short* __restrict__ kb) {
  const int K = 2048;
  __shared__ unsigned short As[128 * 32];
  __shared__ unsigned short Bs[128 * 32];
  const int tid = threadIdx.x;
  const int w = tid >> 6, lane = tid & 63;
  const int quad = lane >> 4, l15 = lane & 15;
  const int m0 = blockIdx.x * 128;
  const int nt = blockIdx.y;                 // 0-15: q head, 16-19: k head
  const int n0 = nt * 128;
  const int mbase = (w >> 1) * 64;
  const f32x4 fzero = {0.f, 0.f, 0.f, 0.f};

  f32x4 acc[4][4];
#pragma unroll
  for (int i = 0; i < 4; i++)
#pragma unroll
    for (int j = 0; j < 4; j++) acc[i][j] = fzero;

  const int srow = w * 16 + (lane >> 2);
  const int scol = (lane & 3) * 8;
  const unsigned short* Ag0 = A + (size_t)(m0 + srow) * K + scol;
  const unsigned short* Ag1 = Ag0 + (size_t)64 * K;
  const unsigned short* Bg0 = B + (size_t)(n0 + srow) * K + scol;
  const unsigned short* Bg1 = Bg0 + (size_t)64 * K;

  for (int k0 = 0; k0 < K; k0 += 32) {
    __syncthreads();
    glds16(Ag0 + k0, &As[w * 512]);
    glds16(Ag1 + k0, &As[2048 + w * 512]);
    glds16(Bg0 + k0, &Bs[w * 512]);
    glds16(Bg1 + k0, &Bs[2048 + w * 512]);
    __syncthreads();
    short8 af[4], bf[4];
#pragma unroll
    for (int mi = 0; mi < 4; mi++)
      af[mi] = *(const short8*)&As[(mbase + mi * 16 + l15) * 32 + quad * 8];
#pragma unroll
    for (int ni = 0; ni < 4; ni++) {
      const int ngrp = (w & 1) * 2 + (ni & 1) + (ni >> 1) * 4;
      bf[ni] = *(const short8*)&Bs[(ngrp * 16 + l15) * 32 + quad * 8];
    }
#pragma unroll
    for (int mi = 0; mi < 4; mi++)
#pragma unroll
      for (int ni = 0; ni < 4; ni++)
        acc[mi][ni] = __builtin_amdgcn_mfma_f32_16x16x32_bf16(af[mi], bf[ni], acc[mi][ni], 0, 0, 0);
  }

  // ---- RoPE epilogue (branchless dst select; nt is wave-uniform)
  const bool isq = nt < 16;
  unsigned short* dst = isq ? qb : kb;
  const int stride = isq ? 2048 : 512;
  const int hoff = (isq ? nt : nt - 16) * 128;
  const float c2 = 0.20762050593045889f;     // log2(10000)/64
  const float inv2pi = 0.15915494309189535f;
#pragma unroll
  for (int ni = 0; ni < 2; ni++) {
    const int i = (w & 1) * 32 + ni * 16 + l15;          // rope dim, < 64
    const float inv_rev = exp2f(-(float)i * c2) * inv2pi; // freq in revolutions
#pragma unroll
    for (int mi = 0; mi < 4; mi++) {
#pragma unroll
      for (int r = 0; r < 4; r++) {
        const int t = m0 + mbase + mi * 16 + quad * 4 + r;
        float rev = (float)t * inv_rev;
        rev = rev - floorf(rev);                   // reduce to [0,1)
        const float sn = __builtin_amdgcn_sinf(rev);   // sin(2*pi*rev)
        const float cs = __builtin_amdgcn_cosf(rev);   // cos(2*pi*rev)
        const float x1 = acc[mi][ni][r], x2 = acc[mi][ni + 2][r];
        unsigned short* p = dst + (size_t)t * stride + hoff + i;
        p[0]  = f2b(x1 * cs - x2 * sn);
        p[64] = f2b(x1 * sn + x2 * cs);
      }
    }
  }
}

// ------------------------------------------------- GEMM V tiles + transposed store
// n-tiles 20..23 (4 v heads); plain fragment mapping; epilogue stores V^T.
__global__ __launch_bounds__(256) void gemm_v(const unsigned short* __restrict__ A,
                                              const unsigned short* __restrict__ B,
                                              unsigned short* __restrict__ vtg) {
  const int K = 2048;
  __shared__ unsigned short As[128 * 32];
  __shared__ unsigned short Bs[128 * 32];
  const int tid = threadIdx.x;
  const int w = tid >> 6, lane = tid & 63;
  const int quad = lane >> 4, l15 = lane & 15;
  const int m0 = blockIdx.x * 128;
  const int g = blockIdx.y;                  // kv group
  const int n0 = (20 + g) * 128;
  const int mbase = (w >> 1) * 64, nbase = (w & 1) * 64;
  const f32x4 fzero = {0.f, 0.f, 0.f, 0.f};

  f32x4 acc[4][4];
#pragma unroll
  for (int i = 0; i < 4; i++)
#pragma unroll
    for (int j = 0; j < 4; j++) acc[i][j] = fzero;

  const int srow = w * 16 + (lane >> 2);
  const int scol = (lane & 3) * 8;
  const unsigned short* Ag0 = A + (size_t)(m0 + srow) * K + scol;
  const unsigned short* Ag1 = Ag0 + (size_t)64 * K;
  const unsigned short* Bg0 = B + (size_t)(n0 + srow) * K + scol;
  const unsigned short* Bg1 = Bg0 + (size_t)64 * K;

  for (int k0 = 0; k0 < K; k0 += 32) {
    __syncthreads();
    glds16(Ag0 + k0, &As[w * 512]);
    glds16(Ag1 + k0, &As[2048 + w * 512]);
    glds16(Bg0 + k0, &Bs[w * 512]);
    glds16(Bg1 + k0, &Bs[2048 + w * 512]);
    __syncthreads();
    short8 af[4], bf[4];
#pragma unroll
    for (int mi = 0; mi < 4; mi++)
      af[mi] = *(const short8*)&As[(mbase + mi * 16 + l15) * 32 + quad * 8];
#pragma unroll
    for (int ni = 0; ni < 4; ni++)
      bf[ni] = *(const short8*)&Bs[(nbase + ni * 16 + l15) * 32 + quad * 8];
#pragma unroll
    for (int mi = 0; mi < 4; mi++)
#pragma unroll
      for (int ni = 0; ni < 4; ni++)
        acc[mi][ni] = __builtin_amdgcn_mfma_f32_16x16x32_bf16(af[mi], bf[ni], acc[mi][ni], 0, 0, 0);
  }

  // ---- transposed store: vtg[g][d][t], t = C-row, d = C-col
#pragma unroll
  for (int mi = 0; mi < 4; mi++) {
    const int tb = m0 + mbase + mi * 16 + quad * 4;
#pragma unroll
    for (int ni = 0; ni < 4; ni++) {
      const int d = nbase + ni * 16 + l15;
      u16x4 o;
#pragma unroll
      for (int r = 0; r < 4; r++) o[r] = f2b(acc[mi][ni][r]);
      *(u16x4*)(vtg + (size_t)(g * 128 + d) * 4096 + tb) = o;
    }
  }
}

// ------------------------------------------------- GEMM C = A * B^T (fp32 out, m97)
__global__ __launch_bounds__(256) void gemm_bt(const unsigned short* __restrict__ A,
                                               const unsigned short* __restrict__ B,
                                               float* __restrict__ Cout,
                                               int M, int N, int K) {
  __shared__ unsigned short As[128 * 32];
  __shared__ unsigned short Bs[128 * 32];
  const int tid = threadIdx.x;
  const int w = tid >> 6, lane = tid & 63;
  const int quad = lane >> 4, l15 = lane & 15;
  const int m0 = blockIdx.x * 128, n0 = blockIdx.y * 128;
  const int mbase = (w >> 1) * 64, nbase = (w & 1) * 64;
  const f32x4 fzero = {0.f, 0.f, 0.f, 0.f};

  f32x4 acc[4][4];
#pragma unroll
  for (int i = 0; i < 4; i++)
#pragma unroll
    for (int j = 0; j < 4; j++) acc[i][j] = fzero;

  const int srow = w * 16 + (lane >> 2);
  const int scol = (lane & 3) * 8;
  const unsigned short* Ag0 = A + (size_t)(m0 + srow) * K + scol;
  const unsigned short* Ag1 = Ag0 + (size_t)64 * K;
  const unsigned short* Bg0 = B + (size_t)(n0 + srow) * K + scol;
  const unsigned short* Bg1 = Bg0 + (size_t)64 * K;

  for (int k0 = 0; k0 < K; k0 += 32) {
    __syncthreads();
    glds16(Ag0 + k0, &As[w * 512]);
    glds16(Ag1 + k0, &As[2048 + w * 512]);
    glds16(Bg0 + k0, &Bs[w * 512]);
    glds16(Bg1 + k0, &Bs[2048 + w * 512]);
    __syncthreads();
    short8 af[4], bf[4];
#pragma unroll
    for (int mi = 0; mi < 4; mi++)
      af[mi] = *(const short8*)&As[(mbase + mi * 16 + l15) * 32 + quad * 8];
#pragma unroll
    for (int ni = 0; ni < 4; ni++)
      bf[ni] = *(const short8*)&Bs[(nbase + ni * 16 + l15) * 32 + quad * 8];
#pragma unroll
    for (int mi = 0; mi < 4; mi++)
#pragma unroll
      for (int ni = 0; ni < 4; ni++)
        acc[mi][ni] = __builtin_amdgcn_mfma_f32_16x16x32_bf16(af[mi], bf[ni], acc[mi][ni], 0, 0, 0);
  }

#pragma unroll
  for (int mi = 0; mi < 4; mi++)
#pragma unroll
    for (int ni = 0; ni < 4; ni++) {
      const int row = m0 + mbase + mi * 16 + quad * 4;
      const int col = n0 + nbase + ni * 16 + l15;
#pragma unroll
      for (int r = 0; r < 4; r++)
        Cout[(size_t)(row + r) * N + col] = acc[mi][ni][r];
    }
}

// ------------------------------------------------------------ windowed GQA attention
// Block: 8 waves, 64 queries, one kv group. wave w: head g*4+(w&3), query-half w>>2.
// All 8 waves share one K/V staging stream.
__global__ __launch_bounds__(512) void attn_fwd(const unsigned short* __restrict__ qp,
                                                const unsigned short* __restrict__ kp,
                                                const unsigned short* __restrict__ vtg,
                                                unsigned short* __restrict__ op) {
  __shared__ unsigned short Ks[2][4][1024];   // [buf][kb][key*32+d']
  __shared__ unsigned short Vt[2][4096];      // [buf][d*32+key]
  const int tid = threadIdx.x;
  const int w = tid >> 6, lane = tid & 63;
  const int quad = lane >> 4, l15 = lane & 15;
  const int t0 = blockIdx.x * 64;
  const int g = blockIdx.y;
  const int h = g * 4 + (w & 3);
  const int t0w = t0 + (w >> 2) * 32;         // this wave's 32-query base
  const f32x4 fzero = {0.f, 0.f, 0.f, 0.f};
  const float scale = 0.088388347648318447f;  // 1/sqrt(128)
  const float NEG_INF = -__builtin_inff();

  short8 qf[4][2];
#pragma unroll
  for (int qt = 0; qt < 2; qt++) {
    const unsigned short* qrow = qp + (size_t)(t0w + qt * 16 + l15) * 2048 + h * 128 + quad * 8;
#pragma unroll
    for (int kb = 0; kb < 4; kb++) qf[kb][qt] = *(const short8*)(qrow + kb * 32);
  }

  f32x4 oacc[8][2];
#pragma unroll
  for (int db = 0; db < 8; db++) { oacc[db][0] = fzero; oacc[db][1] = fzero; }
  float Mrow[2] = {-1.0e30f, -1.0e30f}, Lrow[2] = {0.f, 0.f};

  const int s_begin = (t0 >= 512) ? (t0 - 512) : 0;
  const int nch = ((t0 + 63 - s_begin) >> 5) + 1;

  const int r4 = lane >> 2, c4 = lane & 3;
#define ATTN_STAGE(s0_, b_)                                                              \
  {                                                                                      \
    const int s0v = (s0_);                                                               \
    if (w < 4) {                                                                         \
      _Pragma("unroll")                                                                  \
      for (int p = 0; p < 2; p++)                                                        \
        glds16(kp + (size_t)(s0v + p * 16 + r4) * 512 + g * 128 + w * 32 + c4 * 8,       \
               &Ks[b_][w][p * 512]);                                                     \
    } else {                                                                             \
      const int wv = w - 4;                                                              \
      _Pragma("unroll")                                                                  \
      for (int p = 0; p < 2; p++)                                                        \
        glds16(vtg + (size_t)(g * 128 + wv * 32 + p * 16 + r4) * 4096 + s0v + c4 * 8,    \
               &Vt[b_][wv * 1024 + p * 512]);                                            \
    }                                                                                    \
  }

  ATTN_STAGE(s_begin, 0);

  for (int c = 0; c < nch; ++c) {
    const int s0 = s_begin + c * 32;
    const int b = c & 1;
    __syncthreads();                       // drain glds for chunk c (uniform)
    if (c + 1 < nch) ATTN_STAGE(s_begin + (c + 1) * 32, (c + 1) & 1);

    // wave-relevance: this wave's queries [t0w, t0w+31] vs keys [s0, s0+31]
    if (s0 + 31 >= t0w - 512 && s0 <= t0w + 31) {
      // ---- S^T = K * Q^T, permuted key rows
      f32x4 sacc[2][2];
      sacc[0][0] = fzero; sacc[0][1] = fzero; sacc[1][0] = fzero; sacc[1][1] = fzero;
      const int permBase = ((l15 >> 2) << 3) + (l15 & 3);   // + 4*kt
#pragma unroll
      for (int kb = 0; kb < 4; kb++) {
        short8 af0 = *(const short8*)&Ks[b][kb][(permBase + 0) * 32 + quad * 8];
        short8 af1 = *(const short8*)&Ks[b][kb][(permBase + 4) * 32 + quad * 8];
        sacc[0][0] = __builtin_amdgcn_mfma_f32_16x16x32_bf16(af0, qf[kb][0], sacc[0][0], 0, 0, 0);
        sacc[0][1] = __builtin_amdgcn_mfma_f32_16x16x32_bf16(af0, qf[kb][1], sacc[0][1], 0, 0, 0);
        sacc[1][0] = __builtin_amdgcn_mfma_f32_16x16x32_bf16(af1, qf[kb][0], sacc[1][0], 0, 0, 0);
        sacc[1][1] = __builtin_amdgcn_mfma_f32_16x16x32_bf16(af1, qf[kb][1], sacc[1][1], 0, 0, 0);
      }

      // ---- masked online softmax; key for (kt,r) = s0 + quad*8 + kt*4 + r
      short8 pb[2];
      float alpha[2];
#pragma unroll
      for (int qt = 0; qt < 2; qt++) {
        const int tq = t0w + qt * 16 + l15;
        float vals[8];
        float cmax = NEG_INF;
#pragma unroll
        for (int kt = 0; kt < 2; kt++)
#pragma unroll
          for (int r = 0; r < 4; r++) {
            const int s = s0 + quad * 8 + kt * 4 + r;
            const bool ok = (unsigned)(tq - s) <= 512u;
            const float v = ok ? sacc[kt][qt][r] * scale : NEG_INF;
            vals[kt * 4 + r] = v;
            cmax = fmaxf(cmax, v);
          }
        cmax = fmaxf(cmax, __shfl_xor(cmax, 16));
        cmax = fmaxf(cmax, __shfl_xor(cmax, 32));
        const float Mnew = fmaxf(Mrow[qt], cmax);
        alpha[qt] = __expf(Mrow[qt] - Mnew);
        Mrow[qt] = Mnew;
        float csum = 0.f;
#pragma unroll
        for (int j = 0; j < 8; j++) {
          const float p = __expf(vals[j] - Mnew);   // exp(-inf) = 0 for masked
          csum += p;
          pb[qt][j] = (short)f2b(p);
        }
        csum += __shfl_xor(csum, 16);
        csum += __shfl_xor(csum, 32);
        Lrow[qt] = Lrow[qt] * alpha[qt] + csum;
      }

      // ---- O^T += V^T * P^T
#pragma unroll
      for (int db = 0; db < 8; db++) {
        short8 vf = *(const short8*)&Vt[b][(db * 16 + l15) * 32 + quad * 8];
#pragma unroll
        for (int qt = 0; qt < 2; qt++) {
          oacc[db][qt][0] *= alpha[qt]; oacc[db][qt][1] *= alpha[qt];
          oacc[db][qt][2] *= alpha[qt]; oacc[db][qt][3] *= alpha[qt];
          oacc[db][qt] = __builtin_amdgcn_mfma_f32_16x16x32_bf16(vf, pb[qt], oacc[db][qt], 0, 0, 0);
        }
      }
    }
  }
#undef ATTN_STAGE

#pragma unroll
  for (int qt = 0; qt < 2; qt++) {
    const float invL = 1.f / Lrow[qt];
    unsigned short* orow = op + (size_t)(t0w + qt * 16 + l15) * 2048 + h * 128;
#pragma unroll
    for (int db = 0; db < 8; db++) {
      u16x4 o;
#pragma unroll
      for (int r = 0; r < 4; r++) o[r] = f2b(oacc[db][qt][r] * invL);
      *(u16x4*)(orow + db * 16 + quad * 4) = o;
    }
  }
}

// ---------------------------------------------------------------- launch
extern "C" void kernel_launch(void* const* d_in, const int* in_sizes, int n_in,
                              void* d_out, int out_size, void* d_ws, size_t ws_size,
                              hipStream_t stream) {
  const float* x  = (const float*)d_in[0];
  const float* wq = (const float*)d_in[1];
  const float* wk = (const float*)d_in[2];
  const float* wv = (const float*)d_in[3];
  const float* wo = (const float*)d_in[4];
  float* out = (float*)d_out;
  char* ws = (char*)d_ws;

  // workspace map (~63 MB); attnb aliases xb (dead after gemm_qk/gemm_v)
  unsigned short* xb    = (unsigned short*)(ws + 0);           // 16,777,216 B
  unsigned short* wqkv  = (unsigned short*)(ws + 16777216);    // 12,582,912 B
  unsigned short* wob   = (unsigned short*)(ws + 29360128);    //  8,388,608 B
  unsigned short* qb    = (unsigned short*)(ws + 37748736);    // 16,777,216 B
  unsigned short* kbuf  = (unsigned short*)(ws + 54525952);    //  4,194,304 B
  unsigned short* vtg   = (unsigned short*)(ws + 58720256);    //  4,194,304 B
  unsigned short* attnb = xb;

  cast_all<<<18432, 256, 0, stream>>>(x, wq, wk, wv, wo, (unsigned short*)ws);

  // qkv proj split by epilogue: Q/K (+RoPE) and V (+transpose)
  gemm_qk<<<dim3(32, 20), 256, 0, stream>>>(xb, wqkv, qb, kbuf);
  gemm_v<<<dim3(32, 4), 256, 0, stream>>>(xb, wqkv, vtg);

  attn_fwd<<<dim3(64, 4), 512, 0, stream>>>(qb, kbuf, vtg, attnb);

  // out = attn @ wo^T  (4096 x 2048, K=2048), fp32 out
  gemm_bt<<<dim3(32, 16), 256, 0, stream>>>(attnb, wob, out, 4096, 2048, 2048);
}

// Round 7
// 292.798 us; speedup vs baseline: 1.0252x; 1.0252x over previous
//
#include <hip/hip_runtime.h>

typedef __attribute__((ext_vector_type(8))) short short8;
typedef __attribute__((ext_vector_type(4))) short short4_t;
typedef __attribute__((ext_vector_type(4))) float f32x4;
typedef __attribute__((ext_vector_type(4))) unsigned short u16x4;

__device__ __forceinline__ unsigned short f2b(float f) {
  unsigned int u = __float_as_uint(f);
  u += 0x7fffu + ((u >> 16) & 1u);   // RNE
  return (unsigned short)(u >> 16);
}
__device__ __forceinline__ float b2f(unsigned short s) {
  return __uint_as_float(((unsigned int)s) << 16);
}
__device__ __forceinline__ void glds16(const void* g, void* l) {
  __builtin_amdgcn_global_load_lds(
      (const __attribute__((address_space(1))) unsigned int*)g,
      (__attribute__((address_space(3))) unsigned int*)l, 16, 0, 0);
}

// ------------------------------------------------- fused cast: all 5 inputs -> bf16
__global__ __launch_bounds__(256) void cast_all(const float* __restrict__ x,
                                                const float* __restrict__ wq,
                                                const float* __restrict__ wk,
                                                const float* __restrict__ wv,
                                                const float* __restrict__ wo,
                                                unsigned short* __restrict__ dst) {
  const int i = blockIdx.x * 256 + threadIdx.x;   // < 4,718,592 (grid exact)
  const float* s;
  int off;
  if (i < 2097152)      { s = x;  off = i; }
  else if (i < 3145728) { s = wq; off = i - 2097152; }
  else if (i < 3407872) { s = wk; off = i - 3145728; }
  else if (i < 3670016) { s = wv; off = i - 3407872; }
  else                  { s = wo; off = i - 3670016; }
  f32x4 v = ((const f32x4*)s)[off];
  u16x4 o;
  o[0] = f2b(v[0]); o[1] = f2b(v[1]); o[2] = f2b(v[2]); o[3] = f2b(v[3]);
  ((u16x4*)dst)[i] = o;
}

// ------------------------------------------------- GEMM1 + fused RoPE/V^T epilogue
// Combined 768-block launch (round-6 split to 640+128 regressed: these K-loops are
// per-block latency-bound; fewer resident blocks = less cross-block stall hiding).
// Q tiles are PRE-SCALED by 1/sqrt(128) so attention needs no scale mul.
__global__ __launch_bounds__(256) void gemm_qkv(const unsigned short* __restrict__ A,
                                                const unsigned short* __restrict__ B,
                                                unsigned short* __restrict__ qb,
                                                unsigned short* __restrict__ kb,
                                                unsigned short* __restrict__ vtg) {
  const int K = 2048;
  __shared__ unsigned short As[128 * 32];
  __shared__ unsigned short Bs[128 * 32];
  const int tid = threadIdx.x;
  const int w = tid >> 6, lane = tid & 63;
  const int quad = lane >> 4, l15 = lane & 15;
  const int m0 = blockIdx.x * 128;
  const int nt = blockIdx.y;                 // head tile: 0-15 q, 16-19 k, 20-23 v
  const int n0 = nt * 128;
  const int mbase = (w >> 1) * 64;
  const f32x4 fzero = {0.f, 0.f, 0.f, 0.f};

  f32x4 acc[4][4];
#pragma unroll
  for (int i = 0; i < 4; i++)
#pragma unroll
    for (int j = 0; j < 4; j++) acc[i][j] = fzero;

  const int srow = w * 16 + (lane >> 2);
  const int scol = (lane & 3) * 8;
  const unsigned short* Ag0 = A + (size_t)(m0 + srow) * K + scol;
  const unsigned short* Ag1 = Ag0 + (size_t)64 * K;
  const unsigned short* Bg0 = B + (size_t)(n0 + srow) * K + scol;
  const unsigned short* Bg1 = Bg0 + (size_t)64 * K;

  for (int k0 = 0; k0 < K; k0 += 32) {
    __syncthreads();
    glds16(Ag0 + k0, &As[w * 512]);
    glds16(Ag1 + k0, &As[2048 + w * 512]);
    glds16(Bg0 + k0, &Bs[w * 512]);
    glds16(Bg1 + k0, &Bs[2048 + w * 512]);
    __syncthreads();
    short8 af[4], bf[4];
#pragma unroll
    for (int mi = 0; mi < 4; mi++)
      af[mi] = *(const short8*)&As[(mbase + mi * 16 + l15) * 32 + quad * 8];
#pragma unroll
    for (int ni = 0; ni < 4; ni++) {
      const int ngrp = (w & 1) * 2 + (ni & 1) + (ni >> 1) * 4;
      bf[ni] = *(const short8*)&Bs[(ngrp * 16 + l15) * 32 + quad * 8];
    }
#pragma unroll
    for (int mi = 0; mi < 4; mi++)
#pragma unroll
      for (int ni = 0; ni < 4; ni++)
        acc[mi][ni] = __builtin_amdgcn_mfma_f32_16x16x32_bf16(af[mi], bf[ni], acc[mi][ni], 0, 0, 0);
  }

  if (nt >= 20) {
    // ---- V tile: store transposed into vtg[g][d][t]
    const int g = nt - 20;
#pragma unroll
    for (int mi = 0; mi < 4; mi++) {
      const int tb = m0 + mbase + mi * 16 + quad * 4;
#pragma unroll
      for (int ni = 0; ni < 4; ni++) {
        const int d = ((w & 1) * 2 + (ni & 1) + (ni >> 1) * 4) * 16 + l15;
        u16x4 o;
#pragma unroll
        for (int r = 0; r < 4; r++) o[r] = f2b(acc[mi][ni][r]);
        *(u16x4*)(vtg + (size_t)(g * 128 + d) * 4096 + tb) = o;
      }
    }
  } else {
    // ---- Q/K tile: thread-local RoPE (HW trig), write to qb or kb
    const bool isq = nt < 16;
    unsigned short* dst = isq ? qb : kb;
    const int stride = isq ? 2048 : 512;
    const int hoff = (isq ? nt : nt - 16) * 128;
    const float qsc = isq ? 0.088388347648318447f : 1.0f;  // fold 1/sqrt(128) into Q
    const float c2 = 0.20762050593045889f;   // log2(10000)/64
    const float inv2pi = 0.15915494309189535f;
#pragma unroll
    for (int ni = 0; ni < 2; ni++) {
      const int i = (w & 1) * 32 + ni * 16 + l15;   // rope dim, < 64
      const float inv_rev = exp2f(-(float)i * c2) * inv2pi;  // freq in revolutions
#pragma unroll
      for (int mi = 0; mi < 4; mi++) {
#pragma unroll
        for (int r = 0; r < 4; r++) {
          const int t = m0 + mbase + mi * 16 + quad * 4 + r;
          float rev = (float)t * inv_rev;
          rev = rev - floorf(rev);                 // reduce to [0,1)
          const float sn = __builtin_amdgcn_sinf(rev);   // sin(2*pi*rev)
          const float cs = __builtin_amdgcn_cosf(rev);   // cos(2*pi*rev)
          const float x1 = acc[mi][ni][r], x2 = acc[mi][ni + 2][r];
          unsigned short* p = dst + (size_t)t * stride + hoff + i;
          p[0]  = f2b((x1 * cs - x2 * sn) * qsc);
          p[64] = f2b((x1 * sn + x2 * cs) * qsc);
        }
      }
    }
  }
}

// ------------------------------------------------- GEMM C = A * B^T (fp32 out, m97)
__global__ __launch_bounds__(256) void gemm_bt(const unsigned short* __restrict__ A,
                                               const unsigned short* __restrict__ B,
                                               float* __restrict__ Cout,
                                               int M, int N, int K) {
  __shared__ unsigned short As[128 * 32];
  __shared__ unsigned short Bs[128 * 32];
  const int tid = threadIdx.x;
  const int w = tid >> 6, lane = tid & 63;
  const int quad = lane >> 4, l15 = lane & 15;
  const int m0 = blockIdx.x * 128, n0 = blockIdx.y * 128;
  const int mbase = (w >> 1) * 64, nbase = (w & 1) * 64;
  const f32x4 fzero = {0.f, 0.f, 0.f, 0.f};

  f32x4 acc[4][4];
#pragma unroll
  for (int i = 0; i < 4; i++)
#pragma unroll
    for (int j = 0; j < 4; j++) acc[i][j] = fzero;

  const int srow = w * 16 + (lane >> 2);
  const int scol = (lane & 3) * 8;
  const unsigned short* Ag0 = A + (size_t)(m0 + srow) * K + scol;
  const unsigned short* Ag1 = Ag0 + (size_t)64 * K;
  const unsigned short* Bg0 = B + (size_t)(n0 + srow) * K + scol;
  const unsigned short* Bg1 = Bg0 + (size_t)64 * K;

  for (int k0 = 0; k0 < K; k0 += 32) {
    __syncthreads();
    glds16(Ag0 + k0, &As[w * 512]);
    glds16(Ag1 + k0, &As[2048 + w * 512]);
    glds16(Bg0 + k0, &Bs[w * 512]);
    glds16(Bg1 + k0, &Bs[2048 + w * 512]);
    __syncthreads();
    short8 af[4], bf[4];
#pragma unroll
    for (int mi = 0; mi < 4; mi++)
      af[mi] = *(const short8*)&As[(mbase + mi * 16 + l15) * 32 + quad * 8];
#pragma unroll
    for (int ni = 0; ni < 4; ni++)
      bf[ni] = *(const short8*)&Bs[(nbase + ni * 16 + l15) * 32 + quad * 8];
#pragma unroll
    for (int mi = 0; mi < 4; mi++)
#pragma unroll
      for (int ni = 0; ni < 4; ni++)
        acc[mi][ni] = __builtin_amdgcn_mfma_f32_16x16x32_bf16(af[mi], bf[ni], acc[mi][ni], 0, 0, 0);
  }

#pragma unroll
  for (int mi = 0; mi < 4; mi++)
#pragma unroll
    for (int ni = 0; ni < 4; ni++) {
      const int row = m0 + mbase + mi * 16 + quad * 4;
      const int col = n0 + nbase + ni * 16 + l15;
#pragma unroll
      for (int r = 0; r < 4; r++)
        Cout[(size_t)(row + r) * N + col] = acc[mi][ni][r];
    }
}

// ------------------------------------------------------------ windowed GQA attention
// Block: 4 waves = 4 q-heads of one kv group; 32 queries/block, 64-key chunks.
// Grid 128x4 = 512 blocks -> 2 blocks/CU (cross-block stall hiding; round-6's
// 8-wave/1-block-per-CU version stalled the whole CU at every chunk barrier).
// 64-key chunks halve the per-chunk fixed softmax cost (oacc rescale, shuffles,
// alpha) and the barrier count. Q is pre-scaled by 1/sqrt(128) in gemm_qkv.
// Key permutation per 32-key half hh: A-row m <-> key hh*32 + 8*(m>>2) + 4*kt + (m&3),
// so P^T lands directly in the mfma_16x16x32 B-operand layout (k = quad*8 + kt*4 + r).
__global__ __launch_bounds__(256) void attn_fwd(const unsigned short* __restrict__ qp,
                                                const unsigned short* __restrict__ kp,
                                                const unsigned short* __restrict__ vtg,
                                                unsigned short* __restrict__ op) {
  __shared__ unsigned short Ks[2][4][2048];   // [buf][kb][key*32+d'], key < 64 (16 KB/buf)
  __shared__ unsigned short Vt[2][8192];      // [buf][d*64+key] (16 KB/buf)
  const int tid = threadIdx.x;
  const int w = tid >> 6, lane = tid & 63;
  const int quad = lane >> 4, l15 = lane & 15;
  const int t0 = blockIdx.x * 32;
  const int g = blockIdx.y;
  const int h = g * 4 + w;
  const f32x4 fzero = {0.f, 0.f, 0.f, 0.f};
  const float NEG_INF = -__builtin_inff();

  // Q fragments (pre-scaled): B-operand, n=query=l15, k=d=kb*32+quad*8+j
  short8 qf[4][2];
#pragma unroll
  for (int qt = 0; qt < 2; qt++) {
    const unsigned short* qrow = qp + (size_t)(t0 + qt * 16 + l15) * 2048 + h * 128 + quad * 8;
#pragma unroll
    for (int kb = 0; kb < 4; kb++) qf[kb][qt] = *(const short8*)(qrow + kb * 32);
  }

  f32x4 oacc[8][2];
#pragma unroll
  for (int db = 0; db < 8; db++) { oacc[db][0] = fzero; oacc[db][1] = fzero; }
  float Mrow[2] = {-1.0e30f, -1.0e30f}, Lrow[2] = {0.f, 0.f};

  const int s_begin = (t0 >= 512) ? (t0 - 512) : 0;
  const int nch = ((t0 + 31 - s_begin) >> 6) + 1;

  const int kr = lane >> 2, kc = lane & 3;   // K staging: 16 keys x 4 d-chunks
  const int vr = lane >> 3, vc = lane & 7;   // V staging: 8 d-rows x 8 key-chunks
  // wave w stages K slab kb=w (4 glds16) + V^T d-quarter w (4 glds16)
#define ATTN_STAGE(s0_, b_)                                                              \
  {                                                                                      \
    const int s0v = (s0_);                                                               \
    _Pragma("unroll")                                                                    \
    for (int p = 0; p < 4; p++)                                                          \
      glds16(kp + (size_t)(s0v + p * 16 + kr) * 512 + g * 128 + w * 32 + kc * 8,         \
             &Ks[b_][w][p * 512]);                                                       \
    _Pragma("unroll")                                                                    \
    for (int p = 0; p < 4; p++)                                                          \
      glds16(vtg + (size_t)(g * 128 + w * 32 + p * 8 + vr) * 4096 + s0v + vc * 8,        \
             &Vt[b_][w * 2048 + p * 512]);                                               \
  }

  ATTN_STAGE(s_begin, 0);

  for (int c = 0; c < nch; ++c) {
    const int s0 = s_begin + c * 64;
    const int b = c & 1;
    __syncthreads();                       // drain glds for chunk c
    if (c + 1 < nch) ATTN_STAGE(s0 + 64, b ^ 1);

    // ---- S^T = K * Q^T, permuted key rows, 64 keys x 16 queries per qt
    f32x4 sacc[2][2][2];   // [hh][kt][qt]
#pragma unroll
    for (int hh = 0; hh < 2; hh++)
#pragma unroll
      for (int kt = 0; kt < 2; kt++) { sacc[hh][kt][0] = fzero; sacc[hh][kt][1] = fzero; }
    const int permBase = ((l15 >> 2) << 3) + (l15 & 3);   // + hh*32 + 4*kt
#pragma unroll
    for (int kb = 0; kb < 4; kb++) {
#pragma unroll
      for (int hh = 0; hh < 2; hh++) {
        short8 a0 = *(const short8*)&Ks[b][kb][(hh * 32 + permBase + 0) * 32 + quad * 8];
        short8 a1 = *(const short8*)&Ks[b][kb][(hh * 32 + permBase + 4) * 32 + quad * 8];
        sacc[hh][0][0] = __builtin_amdgcn_mfma_f32_16x16x32_bf16(a0, qf[kb][0], sacc[hh][0][0], 0, 0, 0);
        sacc[hh][0][1] = __builtin_amdgcn_mfma_f32_16x16x32_bf16(a0, qf[kb][1], sacc[hh][0][1], 0, 0, 0);
        sacc[hh][1][0] = __builtin_amdgcn_mfma_f32_16x16x32_bf16(a1, qf[kb][0], sacc[hh][1][0], 0, 0, 0);
        sacc[hh][1][1] = __builtin_amdgcn_mfma_f32_16x16x32_bf16(a1, qf[kb][1], sacc[hh][1][1], 0, 0, 0);
      }
    }

    // ---- masked online softmax; key for (hh,kt,r) = s0 + hh*32 + quad*8 + kt*4 + r
    short8 pb[2][2];   // [hh][qt], j = kt*4 + r
    float alpha[2];
#pragma unroll
    for (int qt = 0; qt < 2; qt++) {
      const int tq = t0 + qt * 16 + l15;
      float vals[2][8];
      float cmax = NEG_INF;
#pragma unroll
      for (int hh = 0; hh < 2; hh++)
#pragma unroll
        for (int kt = 0; kt < 2; kt++)
#pragma unroll
          for (int r = 0; r < 4; r++) {
            const int s = s0 + hh * 32 + quad * 8 + kt * 4 + r;
            const bool ok = (unsigned)(tq - s) <= 512u;
            const float v = ok ? sacc[hh][kt][qt][r] : NEG_INF;   // Q pre-scaled
            vals[hh][kt * 4 + r] = v;
            cmax = fmaxf(cmax, v);
          }
      cmax = fmaxf(cmax, __shfl_xor(cmax, 16));
      cmax = fmaxf(cmax, __shfl_xor(cmax, 32));
      const float Mnew = fmaxf(Mrow[qt], cmax);
      alpha[qt] = __expf(Mrow[qt] - Mnew);
      Mrow[qt] = Mnew;
      float csum = 0.f;
#pragma unroll
      for (int hh = 0; hh < 2; hh++)
#pragma unroll
        for (int j = 0; j < 8; j++) {
          const float p = __expf(vals[hh][j] - Mnew);   // exp(-inf)=0 for masked
          csum += p;
          pb[hh][qt][j] = (short)f2b(p);
        }
      csum += __shfl_xor(csum, 16);
      csum += __shfl_xor(csum, 32);
      Lrow[qt] = Lrow[qt] * alpha[qt] + csum;
    }

    // ---- O^T += V^T * P^T  (two 32-key halves)
#pragma unroll
    for (int db = 0; db < 8; db++) {
      short8 vf0 = *(const short8*)&Vt[b][(db * 16 + l15) * 64 + quad * 8];
      short8 vf1 = *(const short8*)&Vt[b][(db * 16 + l15) * 64 + 32 + quad * 8];
#pragma unroll
      for (int qt = 0; qt < 2; qt++) {
        oacc[db][qt][0] *= alpha[qt]; oacc[db][qt][1] *= alpha[qt];
        oacc[db][qt][2] *= alpha[qt]; oacc[db][qt][3] *= alpha[qt];
        oacc[db][qt] = __builtin_amdgcn_mfma_f32_16x16x32_bf16(vf0, pb[0][qt], oacc[db][qt], 0, 0, 0);
        oacc[db][qt] = __builtin_amdgcn_mfma_f32_16x16x32_bf16(vf1, pb[1][qt], oacc[db][qt], 0, 0, 0);
      }
    }
  }
#undef ATTN_STAGE

#pragma unroll
  for (int qt = 0; qt < 2; qt++) {
    const float invL = 1.f / Lrow[qt];
    unsigned short* orow = op + (size_t)(t0 + qt * 16 + l15) * 2048 + h * 128;
#pragma unroll
    for (int db = 0; db < 8; db++) {
      u16x4 o;
#pragma unroll
      for (int r = 0; r < 4; r++) o[r] = f2b(oacc[db][qt][r] * invL);
      *(u16x4*)(orow + db * 16 + quad * 4) = o;
    }
  }
}

// ---------------------------------------------------------------- launch
extern "C" void kernel_launch(void* const* d_in, const int* in_sizes, int n_in,
                              void* d_out, int out_size, void* d_ws, size_t ws_size,
                              hipStream_t stream) {
  const float* x  = (const float*)d_in[0];
  const float* wq = (const float*)d_in[1];
  const float* wk = (const float*)d_in[2];
  const float* wv = (const float*)d_in[3];
  const float* wo = (const float*)d_in[4];
  float* out = (float*)d_out;
  char* ws = (char*)d_ws;

  // workspace map (~63 MB); attnb aliases xb (dead after gemm_qkv)
  unsigned short* xb    = (unsigned short*)(ws + 0);           // 16,777,216 B
  unsigned short* wqkv  = (unsigned short*)(ws + 16777216);    // 12,582,912 B
  unsigned short* wob   = (unsigned short*)(ws + 29360128);    //  8,388,608 B
  unsigned short* qb    = (unsigned short*)(ws + 37748736);    // 16,777,216 B
  unsigned short* kbuf  = (unsigned short*)(ws + 54525952);    //  4,194,304 B
  unsigned short* vtg   = (unsigned short*)(ws + 58720256);    //  4,194,304 B
  unsigned short* attnb = xb;

  cast_all<<<18432, 256, 0, stream>>>(x, wq, wk, wv, wo, (unsigned short*)ws);

  // qkv proj + fused RoPE (Q pre-scaled) + fused V-transpose
  gemm_qkv<<<dim3(32, 24), 256, 0, stream>>>(xb, wqkv, qb, kbuf, vtg);

  attn_fwd<<<dim3(128, 4), 256, 0, stream>>>(qb, kbuf, vtg, attnb);

  // out = attn @ wo^T  (4096 x 2048, K=2048), fp32 out
  gemm_bt<<<dim3(32, 16), 256, 0, stream>>>(attnb, wob, out, 4096, 2048, 2048);
}